// Round 8
// baseline (4178.584 us; speedup 1.0000x reference)
//
#include <hip/hip_runtime.h>
#include <hip/hip_fp16.h>

#define NN 100000          // N_NODES
#define ED 64              // EMB_DIM
#define NE 3200000         // N_EDGES
#define BSH 9              // log2 nodes per bucket
#define BNODES 512
#define NBUCK 196          // ceil(NN/BNODES)
#define CAP 17408          // slots per bucket (mean 16327, +8.5 sigma), mult of 64
#define CHUNK 8192
#define PTH 512
#define YSTRIDE 65         // LDS y-tile row stride in floats (bank spread)
#define LDSBYTES (BNODES * YSTRIDE * 4)   // 133120

union U32H2 { unsigned u; __half2 h; };
__device__ __forceinline__ float hlo(unsigned v) { U32H2 c; c.u = v; return __low2float(c.h); }
__device__ __forceinline__ float hhi(unsigned v) { U32H2 c; c.u = v; return __high2float(c.h); }

// softmax(attn weights) + init bucket cursors gcur[b] = b*CAP
__global__ void k_init(const float* __restrict__ w, float* __restrict__ attn,
                       int* __restrict__ gcur) {
    int t = threadIdx.x;
    if (t < NBUCK) gcur[t] = t * CAP;
    if (t == 0) {
        float m = fmaxf(fmaxf(w[0], w[1]), fmaxf(w[2], w[3]));
        float e0 = expf(w[0] - m), e1 = expf(w[1] - m), e2 = expf(w[2] - m), e3 = expf(w[3] - m);
        float s = e0 + e1 + e2 + e3;
        attn[0] = e0 / s; attn[1] = e1 / s; attn[2] = e2 / s; attn[3] = e3 / s;
    }
}

// pass 1: partition edges into dst-buckets. entry = attr f32 <<32 | dl 9b <<17 | src 17b
__global__ void __launch_bounds__(PTH) k_part(const int* __restrict__ src,
        const int* __restrict__ dst, const float* __restrict__ attr,
        int* __restrict__ gcur, unsigned long long* __restrict__ part) {
    __shared__ unsigned long long stage[CHUNK];   // 64 KiB
    __shared__ int hist[NBUCK];
    __shared__ int lstart[NBUCK + 1];
    __shared__ int gbase[NBUCK];
    __shared__ unsigned char bkof[CHUNK];         // 8 KiB
    const int tid = threadIdx.x;
    const int base = blockIdx.x * CHUNK;
    const int n = min(CHUNK, NE - base);
    for (int i = tid; i < NBUCK; i += PTH) hist[i] = 0;
    __syncthreads();
    for (int i = tid; i < n; i += PTH) atomicAdd(&hist[dst[base + i] >> BSH], 1);
    __syncthreads();
    if (tid < 64) {                                // exclusive scan of hist
        int carry = 0;
        #pragma unroll
        for (int g = 0; g < 4; ++g) {
            int b = g * 64 + tid;
            int v = (b < NBUCK) ? hist[b] : 0;
            int s = v;
            #pragma unroll
            for (int o = 1; o < 64; o <<= 1) { int t = __shfl_up(s, o, 64); if (tid >= o) s += t; }
            if (b < NBUCK) lstart[b] = carry + s - v;
            carry += __shfl(s, 63, 64);
        }
        if (tid == 0) lstart[NBUCK] = n;
    }
    __syncthreads();
    for (int b = tid; b < NBUCK; b += PTH) {
        int cnt = lstart[b + 1] - lstart[b];
        gbase[b] = atomicAdd(&gcur[b], cnt);
        hist[b] = lstart[b];
    }
    __syncthreads();
    for (int i = tid; i < n; i += PTH) {
        int e = base + i;
        int s = src[e], d = dst[e];
        int bk = d >> BSH;
        int p = atomicAdd(&hist[bk], 1);
        stage[p] = ((unsigned long long)__float_as_uint(attr[e]) << 32)
                 | (unsigned)(s | ((d & (BNODES - 1)) << 17));
        bkof[p] = (unsigned char)bk;
    }
    __syncthreads();
    for (int i = tid; i < n; i += PTH) {
        int bk = bkof[i];
        part[(size_t)gbase[bk] + (i - lstart[bk])] = stage[i];
    }
}

// per-bucket degree histogram (LDS only) -> dinvf
__global__ void __launch_bounds__(512) k_deg(const int* __restrict__ gcur,
        const unsigned long long* __restrict__ part, float* __restrict__ dinvf) {
    __shared__ int h[BNODES];
    const int b = blockIdx.x, tid = threadIdx.x;
    h[tid] = 0;
    __syncthreads();
    const int rs = b * CAP, re = gcur[b];
    for (int j = rs + tid; j < re; j += 512) {
        unsigned lo = (unsigned)part[j];
        atomicAdd(&h[(lo >> 17) & (BNODES - 1)], 1);
    }
    __syncthreads();
    int node = b * BNODES + tid;
    if (node < NN) dinvf[node] = (h[tid] > 0) ? rsqrtf((float)h[tid]) : 0.0f;
}

// pass 2: per dst-bucket counting-sort by src-bucket (ascending) + coef compute.
// Output: es32 (src | dl<<17) and w16 (fp16 coef), padded to multiple of 64.
__global__ void __launch_bounds__(512) k_partB(const int* __restrict__ gcur,
        const unsigned long long* __restrict__ part, const float* __restrict__ dinvf,
        const float* __restrict__ scale,
        unsigned* __restrict__ es32, __half* __restrict__ w16, int* __restrict__ pcnt) {
    __shared__ int hist[NBUCK];
    __shared__ int cur[NBUCK];
    __shared__ float dli[BNODES];
    const int b = blockIdx.x, tid = threadIdx.x;
    const int rs = b * CAP, re = gcur[b];
    const int cnt = re - rs;
    int node = b * BNODES + tid;
    dli[tid] = (node < NN) ? dinvf[node] : 0.0f;
    if (tid < NBUCK) hist[tid] = 0;
    __syncthreads();
    for (int j = rs + tid; j < re; j += 512) {
        unsigned lo = (unsigned)part[j];
        atomicAdd(&hist[(lo & 0x1FFFF) >> BSH], 1);
    }
    __syncthreads();
    if (tid < 64) {                                // exclusive scan -> cursors
        int carry = 0;
        #pragma unroll
        for (int g = 0; g < 4; ++g) {
            int b2 = g * 64 + tid;
            int v = (b2 < NBUCK) ? hist[b2] : 0;
            int s = v;
            #pragma unroll
            for (int o = 1; o < 64; o <<= 1) { int t = __shfl_up(s, o, 64); if (tid >= o) s += t; }
            if (b2 < NBUCK) cur[b2] = rs + carry + s - v;
            carry += __shfl(s, 63, 64);
        }
    }
    __syncthreads();
    const float sc = scale[0];
    for (int j = rs + tid; j < re; j += 512) {
        unsigned long long v = part[j];
        unsigned lo = (unsigned)v;
        int s  = lo & 0x1FFFF;
        int dl = (lo >> 17) & (BNODES - 1);
        float at = __uint_as_float((unsigned)(v >> 32));
        float c = dinvf[s] * dli[dl] * expf(sc * at);
        int p = atomicAdd(&cur[s >> BSH], 1);
        es32[p] = lo & 0x03FFFFFFu;
        w16[p] = __float2half(c);
    }
    __syncthreads();
    int pc = (cnt + 63) & ~63;                     // pad to multiple of 64 edges
    for (int p = cnt + tid; p < pc; p += 512) { es32[rs + p] = 0; w16[rs + p] = __float2half(0.0f); }
    if (tid == 0) pcnt[b] = pc;
}

// x0 = fp16(emb). grid = NN*ED/4/256 = 6250 exact
__global__ void k_prep(const float* __restrict__ emb, unsigned short* __restrict__ x0) {
    int i = blockIdx.x * 256 + threadIdx.x;
    float4 e = reinterpret_cast<const float4*>(emb)[i];
    ushort4 u;
    u.x = __half_as_ushort(__float2half(e.x));
    u.y = __half_as_ushort(__float2half(e.y));
    u.z = __half_as_ushort(__float2half(e.z));
    u.w = __half_as_ushort(__float2half(e.w));
    reinterpret_cast<ushort4*>(x0)[i] = u;
}

// SpMM: block = dst-bucket; y-tile f32 in LDS; edges (src-bucket ascending)
// processed 4 per wave-iter (16 lanes/edge, uint2 = 4 fp16 dims per lane).
// All 196 blocks co-resident sweep src in lockstep -> x window L2-hot.
template <bool FINAL>
__global__ void __launch_bounds__(1024) k_spmm(const int* __restrict__ pcnt,
        const unsigned* __restrict__ es32, const unsigned* __restrict__ w16u,
        const unsigned short* __restrict__ x, unsigned short* __restrict__ y,
        const float* __restrict__ emb, const unsigned short* __restrict__ y1,
        const float* __restrict__ attnp, float* __restrict__ out0,
        float* __restrict__ acc) {
    extern __shared__ float yt[];                  // [BNODES][YSTRIDE]
    const int b = blockIdx.x;
    const int tid = threadIdx.x;
    for (int i = tid; i < BNODES * YSTRIDE; i += 1024) yt[i] = 0.0f;
    const int rs = b * CAP;
    const int jend = rs + pcnt[b];
    const int wid = tid >> 6, lane = tid & 63;
    const int g = lane >> 4, gi = lane & 15;
    __syncthreads();

    int jq = rs + wid * 4;                         // this wave's quad; stride 64 edges
    jq = __builtin_amdgcn_readfirstlane(jq);
    // --- software pipeline: meta 2 ahead, x 1 ahead ---
    unsigned u0, u1; float w0, w1; uint2 v0;
    {   // meta(jq)
        unsigned a0 = es32[jq], a1 = es32[jq + 1], a2 = es32[jq + 2], a3 = es32[jq + 3];
        unsigned p0 = w16u[(jq >> 1)], p1 = w16u[(jq >> 1) + 1];
        unsigned ua = (g & 1) ? a1 : a0, ub = (g & 1) ? a3 : a2;
        u0 = (g & 2) ? ub : ua;
        unsigned wp = (g & 2) ? p1 : p0;
        w0 = (g & 1) ? hhi(wp) : hlo(wp);
    }
    {   // meta(jq+64)
        int j2 = jq + 64;
        unsigned a0 = es32[j2], a1 = es32[j2 + 1], a2 = es32[j2 + 2], a3 = es32[j2 + 3];
        unsigned p0 = w16u[(j2 >> 1)], p1 = w16u[(j2 >> 1) + 1];
        unsigned ua = (g & 1) ? a1 : a0, ub = (g & 1) ? a3 : a2;
        u1 = (g & 2) ? ub : ua;
        unsigned wp = (g & 2) ? p1 : p0;
        w1 = (g & 1) ? hhi(wp) : hlo(wp);
    }
    v0 = reinterpret_cast<const uint2*>(x)[(u0 & 0x1FFFFu) * 16u + gi];

    for (; jq < jend; ) {
        // prefetch meta(jq+128)
        int j3 = jq + 128;
        unsigned u2; float w2;
        {
            unsigned a0 = es32[j3], a1 = es32[j3 + 1], a2 = es32[j3 + 2], a3 = es32[j3 + 3];
            unsigned p0 = w16u[(j3 >> 1)], p1 = w16u[(j3 >> 1) + 1];
            unsigned ua = (g & 1) ? a1 : a0, ub = (g & 1) ? a3 : a2;
            u2 = (g & 2) ? ub : ua;
            unsigned wp = (g & 2) ? p1 : p0;
            w2 = (g & 1) ? hhi(wp) : hlo(wp);
        }
        // prefetch x(jq+64)
        uint2 v1 = reinterpret_cast<const uint2*>(x)[(u1 & 0x1FFFFu) * 16u + gi];
        // process current
        {
            unsigned dl = u0 >> 17;
            float* row = yt + dl * YSTRIDE + gi * 4;
            atomicAdd(row + 0, w0 * hlo(v0.x));
            atomicAdd(row + 1, w0 * hhi(v0.x));
            atomicAdd(row + 2, w0 * hlo(v0.y));
            atomicAdd(row + 3, w0 * hhi(v0.y));
        }
        jq += 64;
        u0 = u1; w0 = w1; v0 = v1;
        u1 = u2; w1 = w2;
    }
    __syncthreads();

    // flush: 2 threads per row, 32 dims each
    int r = tid >> 1, hf = tid & 1;
    int node = b * BNODES + r;
    if (node < NN) {
        const float* row = yt + r * YSTRIDE + hf * 32;
        if (!FINAL) {
            uint2* dst = reinterpret_cast<uint2*>(y) + (size_t)node * 16 + hf * 8;
            #pragma unroll
            for (int i = 0; i < 8; ++i) {
                U32H2 q0, q1;
                q0.h = __floats2half2_rn(row[i * 4 + 0], row[i * 4 + 1]);
                q1.h = __floats2half2_rn(row[i * 4 + 2], row[i * 4 + 3]);
                dst[i] = make_uint2(q0.u, q1.u);
            }
        } else {
            float a0 = attnp[0], a1 = attnp[1], a2 = attnp[2], a3 = attnp[3];
            size_t o = (size_t)node * 16 + hf * 8;
            const float4* e4 = reinterpret_cast<const float4*>(emb) + o;
            const uint2* y1v = reinterpret_cast<const uint2*>(y1) + o;
            const uint2* y2v = reinterpret_cast<const uint2*>(x) + o;   // x == y2
            float4* o4 = reinterpret_cast<float4*>(out0) + o;
            float4* a4 = reinterpret_cast<float4*>(acc) + o;
            #pragma unroll
            for (int i = 0; i < 8; ++i) {
                float4 e = e4[i];
                uint2 q1 = y1v[i], q2 = y2v[i];
                float4 rr;
                rr.x = a0 * e.x + a1 * hlo(q1.x) + a2 * hlo(q2.x) + a3 * row[i * 4 + 0];
                rr.y = a0 * e.y + a1 * hhi(q1.x) + a2 * hhi(q2.x) + a3 * row[i * 4 + 1];
                rr.z = a0 * e.z + a1 * hlo(q1.y) + a2 * hlo(q2.y) + a3 * row[i * 4 + 2];
                rr.w = a0 * e.w + a1 * hhi(q1.y) + a2 * hhi(q2.y) + a3 * row[i * 4 + 3];
                o4[i] = e;
                a4[i] = rr;
            }
        }
    }
}

extern "C" void kernel_launch(void* const* d_in, const int* in_sizes, int n_in,
                              void* d_out, int out_size, void* d_ws, size_t ws_size,
                              hipStream_t stream) {
    const float* emb   = (const float*)d_in[0];
    const float* attw  = (const float*)d_in[1];
    const float* scale = (const float*)d_in[2];
    const float* attr  = (const float*)d_in[3];
    const int*   ei    = (const int*)d_in[4];
    const int* src = ei;
    const int* dst = ei + NE;

    float* out0 = (float*)d_out;
    float* acc  = out0 + (size_t)NN * ED;

    // allow >64KB dynamic LDS (133,120 B) for the spmm kernels (idempotent)
    hipFuncSetAttribute(reinterpret_cast<const void*>(k_spmm<false>),
                        hipFuncAttributeMaxDynamicSharedMemorySize, LDSBYTES);
    hipFuncSetAttribute(reinterpret_cast<const void*>(k_spmm<true>),
                        hipFuncAttributeMaxDynamicSharedMemorySize, LDSBYTES);

    // workspace (~61.5 MB). part dead after k_partB -> aliased by x0,y1.
    const size_t SLOTS = (size_t)NBUCK * CAP + 256;   // +overshoot pad
    char* ws = (char*)d_ws;
    size_t off = 0;
    float*  attn  = (float*)(ws + off); off += 256;
    int*    gcur  = (int*)(ws + off);   off += 1024;
    int*    pcnt  = (int*)(ws + off);   off += 1024;
    float*  dinvf = (float*)(ws + off); off += ((size_t)NN * 4 + 255) & ~(size_t)255;
    unsigned long long* part = (unsigned long long*)(ws + off); off += SLOTS * 8;
    unsigned* es32 = (unsigned*)(ws + off); off += SLOTS * 4;
    __half*  w16  = (__half*)(ws + off);    off += SLOTS * 2;
    unsigned short* y2 = (unsigned short*)(ws + off); off += (size_t)NN * ED * 2;
    unsigned short* x0 = (unsigned short*)part;                     // alias
    unsigned short* y1 = (unsigned short*)part + (size_t)NN * ED;   // alias

    const int VB = (NN * ED / 4) / 256;        // 6250 exact
    const int PB = (NE + CHUNK - 1) / CHUNK;   // 391

    k_init<<<1, 256, 0, stream>>>(attw, attn, gcur);
    k_part<<<PB, PTH, 0, stream>>>(src, dst, attr, gcur, part);
    k_deg<<<NBUCK, 512, 0, stream>>>(gcur, part, dinvf);
    k_partB<<<NBUCK, 512, 0, stream>>>(gcur, part, dinvf, scale, es32, w16, pcnt);

    k_prep<<<VB, 256, 0, stream>>>(emb, x0);   // part dead; x0/y1 alias it

    const unsigned* w16u = reinterpret_cast<const unsigned*>(w16);
    k_spmm<false><<<NBUCK, 1024, LDSBYTES, stream>>>(pcnt, es32, w16u, x0, y1,
                                                     nullptr, nullptr, nullptr, nullptr, nullptr);
    k_spmm<false><<<NBUCK, 1024, LDSBYTES, stream>>>(pcnt, es32, w16u, y1, y2,
                                                     nullptr, nullptr, nullptr, nullptr, nullptr);
    k_spmm<true><<<NBUCK, 1024, LDSBYTES, stream>>>(pcnt, es32, w16u, y2, nullptr,
                                                    emb, y1, attn, out0, acc);
}

// Round 9
// 292.404 us; speedup vs baseline: 14.2904x; 14.2904x over previous
//
#include <hip/hip_runtime.h>
#include <hip/hip_fp16.h>

#define NN 100000          // N_NODES
#define ED 64              // EMB_DIM
#define NE 3200000         // N_EDGES
#define BSH 9              // log2 nodes per bucket
#define BNODES 512
#define NBUCK 196          // ceil(NN/BNODES)
#define CAP 17408          // slots per bucket (mean 16384, +8 sigma), mult of 64
#define CHUNK 8192
#define PTH 512
#define NEP (NE + 8 * NN)  // padded edge capacity
#define PLACE_LDS (CAP * 8 + 512 * 4 * 3 + 256 * 4)   // 146432 B

union U32H2 { unsigned u; __half2 h; };
__device__ __forceinline__ float h2lo(unsigned u) { U32H2 c; c.u = u; return __low2float(c.h); }
__device__ __forceinline__ float h2hi(unsigned u) { U32H2 c; c.u = u; return __high2float(c.h); }

// softmax(attn weights) + init bucket cursors gcur[b] = b*CAP
__global__ void k_init(const float* __restrict__ w, float* __restrict__ attn,
                       int* __restrict__ gcur) {
    int t = threadIdx.x;
    if (t < NBUCK) gcur[t] = t * CAP;
    if (t == 0) {
        float m = fmaxf(fmaxf(w[0], w[1]), fmaxf(w[2], w[3]));
        float e0 = expf(w[0] - m), e1 = expf(w[1] - m), e2 = expf(w[2] - m), e3 = expf(w[3] - m);
        float s = e0 + e1 + e2 + e3;
        attn[0] = e0 / s; attn[1] = e1 / s; attn[2] = e2 / s; attn[3] = e3 / s;
    }
}

// pass 1: partition edges into fixed-CAP dst-buckets.
// entry = attr f32 <<32 | dl 9b <<17 | src 17b
__global__ void __launch_bounds__(PTH) k_part(const int* __restrict__ src,
        const int* __restrict__ dst, const float* __restrict__ attr,
        int* __restrict__ gcur, unsigned long long* __restrict__ part) {
    __shared__ unsigned long long stage[CHUNK];   // 64 KiB
    __shared__ int hist[NBUCK];
    __shared__ int lstart[NBUCK + 1];
    __shared__ int gbase[NBUCK];
    __shared__ unsigned char bkof[CHUNK];         // 8 KiB
    const int tid = threadIdx.x;
    const int base = blockIdx.x * CHUNK;
    const int n = min(CHUNK, NE - base);
    for (int i = tid; i < NBUCK; i += PTH) hist[i] = 0;
    __syncthreads();
    for (int i = tid; i < n; i += PTH) atomicAdd(&hist[dst[base + i] >> BSH], 1);
    __syncthreads();
    if (tid < 64) {                                // exclusive scan of hist
        int carry = 0;
        #pragma unroll
        for (int g = 0; g < 4; ++g) {
            int b = g * 64 + tid;
            int v = (b < NBUCK) ? hist[b] : 0;
            int s = v;
            #pragma unroll
            for (int o = 1; o < 64; o <<= 1) { int t = __shfl_up(s, o, 64); if (tid >= o) s += t; }
            if (b < NBUCK) lstart[b] = carry + s - v;
            carry += __shfl(s, 63, 64);
        }
        if (tid == 0) lstart[NBUCK] = n;
    }
    __syncthreads();
    for (int b = tid; b < NBUCK; b += PTH) {
        int cnt = lstart[b + 1] - lstart[b];
        gbase[b] = atomicAdd(&gcur[b], cnt);
        hist[b] = lstart[b];
    }
    __syncthreads();
    for (int i = tid; i < n; i += PTH) {
        int e = base + i;
        int s = src[e], d = dst[e];
        int bk = d >> BSH;
        int p = atomicAdd(&hist[bk], 1);
        stage[p] = ((unsigned long long)__float_as_uint(attr[e]) << 32)
                 | (unsigned)(s | ((d & (BNODES - 1)) << 17));
        bkof[p] = (unsigned char)bk;
    }
    __syncthreads();
    for (int i = tid; i < n; i += PTH) {
        int bk = bkof[i];
        part[(size_t)gbase[bk] + (i - lstart[bk])] = stage[i];
    }
}

// per-bucket degree histogram + PADDED (mult-8) local scan.
// rowptr[node] <- local padded offset; dinvf <- rsqrt(deg); pbsum[b] <- padded total
__global__ void __launch_bounds__(512) k_ndeg(const int* __restrict__ gcur,
        const unsigned long long* __restrict__ part,
        int* __restrict__ rowptr, float* __restrict__ dinvf, int* __restrict__ pbsum) {
    __shared__ int h[BNODES];
    __shared__ int wsum[8];
    const int b = blockIdx.x, tid = threadIdx.x;
    const int lane = tid & 63, wv = tid >> 6;
    h[tid] = 0;
    __syncthreads();
    const int rs = b * CAP, re = gcur[b];
    for (int j = rs + tid; j < re; j += 512) {
        unsigned lo = (unsigned)part[j];
        atomicAdd(&h[(lo >> 17) & (BNODES - 1)], 1);
    }
    __syncthreads();
    int deg = h[tid];
    int pd = (deg + 7) & ~7;
    int x = pd;
    #pragma unroll
    for (int o = 1; o < 64; o <<= 1) { int t = __shfl_up(x, o, 64); if (lane >= o) x += t; }
    if (lane == 63) wsum[wv] = x;
    __syncthreads();
    if (tid < 8) {
        int orig = wsum[tid]; int t = orig;
        #pragma unroll
        for (int o = 1; o < 8; o <<= 1) { int u = __shfl_up(t, o, 64); if (tid >= o) t += u; }
        wsum[tid] = t - orig;
    }
    __syncthreads();
    int node = b * BNODES + tid;
    int lofs = wsum[wv] + (x - pd);              // exclusive padded offset in bucket
    if (node < NN) {
        rowptr[node] = lofs;
        dinvf[node] = (deg > 0) ? rsqrtf((float)deg) : 0.0f;
    }
    if (tid == 511) pbsum[b] = wsum[7] + x;      // bucket padded total
}

// scan pbsum -> pbase[NBUCK+1]; rowptr[NN] = grand padded total
__global__ void k_pbscan(const int* __restrict__ pbsum, int* __restrict__ pbase,
                         int* __restrict__ rowptr) {
    int tid = threadIdx.x;  // 64
    int carry = 0;
    #pragma unroll
    for (int g = 0; g < 4; ++g) {
        int b = g * 64 + tid;
        int v = (b < NBUCK) ? pbsum[b] : 0;
        int s = v;
        #pragma unroll
        for (int o = 1; o < 64; o <<= 1) { int t = __shfl_up(s, o, 64); if (tid >= o) s += t; }
        if (b < NBUCK) pbase[b] = carry + s - v;
        carry += __shfl(s, 63, 64);
    }
    if (tid == 0) { pbase[NBUCK] = carry; rowptr[NN] = carry; }
}

// pass 2: counting-sort bucket edges by src-bucket into LDS (computing coef),
// then drain IN ORDER through per-row atomic cursors -> rows end up
// approximately src-ascending (locality for the gather's lockstep sweep).
// Also zero-fills pad slots and finalizes rowptr to global padded starts.
__global__ void __launch_bounds__(512) k_place2(const int* __restrict__ gcur,
        const int* __restrict__ pbase, const int* __restrict__ pbsum,
        const unsigned long long* __restrict__ part,
        const float* __restrict__ dinvf, const float* __restrict__ scale,
        int* __restrict__ rowptr, int* __restrict__ es, __half* __restrict__ ew) {
    extern __shared__ unsigned long long stage[];            // CAP entries
    int*   cur    = (int*)(stage + CAP);                     // 512
    int*   lofs_s = cur + 512;                               // 512
    float* dli    = (float*)(lofs_s + 512);                  // 512
    int*   sbcur  = (int*)(dli + 512);                       // 256
    const int b = blockIdx.x, tid = threadIdx.x;
    const int rs = b * CAP, re = gcur[b];
    const int cnt = re - rs;
    const int base = pbase[b];
    const int ltot = pbsum[b];
    const int node = b * BNODES + tid;
    int lofs = (node < NN) ? rowptr[node] : ltot;
    lofs_s[tid] = lofs;
    cur[tid] = base + lofs;
    dli[tid] = (node < NN) ? dinvf[node] : 0.0f;
    if (tid < 256) sbcur[tid] = 0;
    __syncthreads();
    // histogram of src-buckets
    for (int j = rs + tid; j < re; j += 512) {
        unsigned lo = (unsigned)part[j];
        atomicAdd(&sbcur[(lo & 0x1FFFF) >> BSH], 1);
    }
    __syncthreads();
    if (tid < 64) {                                // exclusive scan -> cursors
        int carry = 0;
        #pragma unroll
        for (int g = 0; g < 4; ++g) {
            int b2 = g * 64 + tid;
            int v = (b2 < NBUCK) ? sbcur[b2] : 0;
            int s = v;
            #pragma unroll
            for (int o = 1; o < 64; o <<= 1) { int t = __shfl_up(s, o, 64); if (tid >= o) s += t; }
            if (b2 < NBUCK) sbcur[b2] = carry + s - v;
            carry += __shfl(s, 63, 64);
        }
    }
    __syncthreads();
    // coef + scatter into LDS stage sorted by src-bucket
    const float sc = scale[0];
    for (int j = rs + tid; j < re; j += 512) {
        unsigned long long v = part[j];
        unsigned lo = (unsigned)v;
        int s  = lo & 0x1FFFF;
        int dl = (lo >> 17) & (BNODES - 1);
        float at = __uint_as_float((unsigned)(v >> 32));
        float c = dinvf[s] * dli[dl] * expf(sc * at);
        int p = atomicAdd(&sbcur[s >> BSH], 1);
        stage[p] = ((unsigned long long)__float_as_uint(c) << 32)
                 | (unsigned)(lo & 0x03FFFFFFu);
    }
    __syncthreads();
    // in-order drain: preserves src order per row to ~one-iteration granularity
    for (int j = tid; j < cnt; j += 512) {
        unsigned long long v = stage[j];
        unsigned lo = (unsigned)v;
        int s  = lo & 0x1FFFF;
        int dl = (lo >> 17) & (BNODES - 1);
        float c = __uint_as_float((unsigned)(v >> 32));
        int p = atomicAdd(&cur[dl], 1);
        es[p] = s;
        ew[p] = __float2half(c);
    }
    __syncthreads();
    int rowend = base + ((tid == 511) ? ltot : lofs_s[tid + 1]);
    for (int p = cur[tid]; p < rowend; ++p) { es[p] = 0; ew[p] = __float2half(0.0f); }
    if (node < NN) rowptr[node] = base + lofs;   // final padded row start
}

// x0 = fp16(emb). grid = NN*ED/4/256 = 6250 exact
__global__ void k_prep(const float* __restrict__ emb, unsigned short* __restrict__ x0) {
    int i = blockIdx.x * 256 + threadIdx.x;
    float4 e = reinterpret_cast<const float4*>(emb)[i];
    ushort4 u;
    u.x = __half_as_ushort(__float2half(e.x));
    u.y = __half_as_ushort(__float2half(e.y));
    u.z = __half_as_ushort(__float2half(e.z));
    u.w = __half_as_ushort(__float2half(e.w));
    reinterpret_cast<ushort4*>(x0)[i] = u;
}

// gather: one wave per node; 4 lane-groups of 16 handle 4 edges at once;
// each lane loads uint2 = 4 fp16 dims. Rows padded to multiple of 8 edges.
// FINAL: fused epilogue writes out0 = emb and acc = w0*emb+w1*y1+w2*y2+w3*P(y2).
template <bool FINAL>
__global__ void __launch_bounds__(256) k_gather(const int* __restrict__ rowptr,
        const int* __restrict__ es, const __half* __restrict__ ew,
        const unsigned short* __restrict__ x, unsigned short* __restrict__ y,
        const unsigned short* __restrict__ y1, const float* __restrict__ emb,
        const float* __restrict__ attnp, float* __restrict__ out0,
        float* __restrict__ acc) {
    int gt = blockIdx.x * 256 + threadIdx.x;   // grid = NN*64/256 = 25000 exact
    int nid = gt >> 6;                         // wave-uniform
    int lane = gt & 63;
    int g = lane >> 4;                         // edge slot 0..3
    int gi = lane & 15;                        // dword-pair index (4 dims)
    int beg = __builtin_amdgcn_readfirstlane(rowptr[nid]);
    int end = __builtin_amdgcn_readfirstlane(rowptr[nid + 1]);
    const unsigned* ewu = reinterpret_cast<const unsigned*>(ew);
    const uint2* xv = reinterpret_cast<const uint2*>(x);
    float a0 = 0.0f, a1 = 0.0f, a2 = 0.0f, a3 = 0.0f;
    for (int j = beg; j < end; j += 8) {
        #pragma unroll
        for (int k = 0; k < 2; ++k) {
            int jj = j + 4 * k;
            int s0 = es[jj], s1 = es[jj + 1], s2 = es[jj + 2], s3 = es[jj + 3];
            unsigned w01 = ewu[(jj >> 1)], w23 = ewu[(jj >> 1) + 1];
            int sA = (g & 1) ? s1 : s0;
            int sB = (g & 1) ? s3 : s2;
            int s = (g & 2) ? sB : sA;
            unsigned wp = (g & 2) ? w23 : w01;
            float w = (g & 1) ? h2hi(wp) : h2lo(wp);
            uint2 u = xv[(size_t)s * 16 + gi];
            a0 += w * h2lo(u.x); a1 += w * h2hi(u.x);
            a2 += w * h2lo(u.y); a3 += w * h2hi(u.y);
        }
    }
    a0 += __shfl_xor(a0, 16, 64); a0 += __shfl_xor(a0, 32, 64);
    a1 += __shfl_xor(a1, 16, 64); a1 += __shfl_xor(a1, 32, 64);
    a2 += __shfl_xor(a2, 16, 64); a2 += __shfl_xor(a2, 32, 64);
    a3 += __shfl_xor(a3, 16, 64); a3 += __shfl_xor(a3, 32, 64);
    if (lane < 16) {
        size_t ri = (size_t)nid * 16 + gi;     // uint2-granular row slot
        if (!FINAL) {
            U32H2 o01, o23;
            o01.h = __floats2half2_rn(a0, a1);
            o23.h = __floats2half2_rn(a2, a3);
            uint2 o; o.x = o01.u; o.y = o23.u;
            reinterpret_cast<uint2*>(y)[ri] = o;
        } else {
            float w0 = attnp[0], w1 = attnp[1], w2 = attnp[2], w3 = attnp[3];
            float4 e = reinterpret_cast<const float4*>(emb)[ri];
            uint2 v1 = reinterpret_cast<const uint2*>(y1)[ri];
            uint2 v2 = xv[ri];                 // y2 row of this node
            float4 r;
            r.x = w0 * e.x + w1 * h2lo(v1.x) + w2 * h2lo(v2.x) + w3 * a0;
            r.y = w0 * e.y + w1 * h2hi(v1.x) + w2 * h2hi(v2.x) + w3 * a1;
            r.z = w0 * e.z + w1 * h2lo(v1.y) + w2 * h2lo(v2.y) + w3 * a2;
            r.w = w0 * e.w + w1 * h2hi(v1.y) + w2 * h2hi(v2.y) + w3 * a3;
            reinterpret_cast<float4*>(out0)[ri] = e;
            reinterpret_cast<float4*>(acc)[ri] = r;
        }
    }
}

extern "C" void kernel_launch(void* const* d_in, const int* in_sizes, int n_in,
                              void* d_out, int out_size, void* d_ws, size_t ws_size,
                              hipStream_t stream) {
    const float* emb   = (const float*)d_in[0];
    const float* attw  = (const float*)d_in[1];
    const float* scale = (const float*)d_in[2];
    const float* attr  = (const float*)d_in[3];
    const int*   ei    = (const int*)d_in[4];
    const int* src = ei;
    const int* dst = ei + NE;

    float* out0 = (float*)d_out;
    float* acc  = out0 + (size_t)NN * ED;

    // allow 146 KB dynamic LDS for k_place2
    hipFuncSetAttribute(reinterpret_cast<const void*>(k_place2),
                        hipFuncAttributeMaxDynamicSharedMemorySize, PLACE_LDS);

    // workspace (~65 MB). part (27.3MB) dead after k_place2 -> aliased by x0,y1.
    const size_t SLOTS = (size_t)NBUCK * CAP;   // 3,411,968
    char* ws = (char*)d_ws;
    size_t off = 0;
    float*  attn  = (float*)(ws + off); off += 256;
    int*    gcur  = (int*)(ws + off);   off += 1024;
    int*    pbsum = (int*)(ws + off);   off += 1024;
    int*    pbase = (int*)(ws + off);   off += 1024;
    float*  dinvf = (float*)(ws + off); off += ((size_t)NN * 4 + 255) & ~(size_t)255;
    int*    rowptr= (int*)(ws + off);   off += ((size_t)(NN + 1) * 4 + 255) & ~(size_t)255;
    unsigned long long* part = (unsigned long long*)(ws + off); off += SLOTS * 8;
    int*    es    = (int*)(ws + off);   off += (size_t)NEP * 4;
    __half* ew    = (__half*)(ws + off);off += (size_t)NEP * 2;
    unsigned short* y2 = (unsigned short*)(ws + off); off += (size_t)NN * ED * 2;
    unsigned short* x0 = (unsigned short*)part;                     // alias
    unsigned short* y1 = (unsigned short*)part + (size_t)NN * ED;   // alias

    const int VB = (NN * ED / 4) / 256;        // 6250 exact
    const int GB = (NN * ED) / 256;            // 25000 exact
    const int PB = (NE + CHUNK - 1) / CHUNK;   // 391

    k_init<<<1, 256, 0, stream>>>(attw, attn, gcur);
    k_part<<<PB, PTH, 0, stream>>>(src, dst, attr, gcur, part);
    k_ndeg<<<NBUCK, 512, 0, stream>>>(gcur, part, rowptr, dinvf, pbsum);
    k_pbscan<<<1, 64, 0, stream>>>(pbsum, pbase, rowptr);
    k_place2<<<NBUCK, 512, PLACE_LDS, stream>>>(gcur, pbase, pbsum, part, dinvf,
                                                scale, rowptr, es, ew);

    k_prep<<<VB, 256, 0, stream>>>(emb, x0);   // part dead; x0/y1 alias it

    k_gather<false><<<GB, 256, 0, stream>>>(rowptr, es, ew, x0, y1, nullptr, nullptr, nullptr, nullptr, nullptr);
    k_gather<false><<<GB, 256, 0, stream>>>(rowptr, es, ew, y1, y2, nullptr, nullptr, nullptr, nullptr, nullptr);
    k_gather<true><<<GB, 256, 0, stream>>>(rowptr, es, ew, y2, nullptr, y1, emb, attn, out0, acc);
}

// Round 10
// 272.660 us; speedup vs baseline: 15.3252x; 1.0724x over previous
//
#include <hip/hip_runtime.h>
#include <hip/hip_fp16.h>

#define NN 100000          // N_NODES
#define ED 64              // EMB_DIM
#define NE 3200000         // N_EDGES
#define BSH 9              // log2 nodes per bucket
#define BNODES 512
#define NBUCK 196          // ceil(NN/BNODES)
#define CAP 17408          // slots per bucket (mean 16384, +8 sigma), mult of 64
#define CHUNK 8192
#define PTH 512
#define NEP (NE + 8 * NN)  // padded edge capacity (rows padded to mult of 8)

union U32H2 { unsigned u; __half2 h; };
__device__ __forceinline__ float h2lo(unsigned u) { U32H2 c; c.u = u; return __low2float(c.h); }
__device__ __forceinline__ float h2hi(unsigned u) { U32H2 c; c.u = u; return __high2float(c.h); }

// softmax(attn weights) + init bucket cursors gcur[b] = b*CAP
__global__ void k_init(const float* __restrict__ w, float* __restrict__ attn,
                       int* __restrict__ gcur) {
    int t = threadIdx.x;
    if (t < NBUCK) gcur[t] = t * CAP;
    if (t == 0) {
        float m = fmaxf(fmaxf(w[0], w[1]), fmaxf(w[2], w[3]));
        float e0 = expf(w[0] - m), e1 = expf(w[1] - m), e2 = expf(w[2] - m), e3 = expf(w[3] - m);
        float s = e0 + e1 + e2 + e3;
        attn[0] = e0 / s; attn[1] = e1 / s; attn[2] = e2 / s; attn[3] = e3 / s;
    }
}

// pass 1: partition edges into fixed-CAP dst-buckets.
// entry = attr f32 <<32 | dl 9b <<17 | src 17b
__global__ void __launch_bounds__(PTH) k_part(const int* __restrict__ src,
        const int* __restrict__ dst, const float* __restrict__ attr,
        int* __restrict__ gcur, unsigned long long* __restrict__ part) {
    __shared__ unsigned long long stage[CHUNK];   // 64 KiB
    __shared__ int hist[NBUCK];
    __shared__ int lstart[NBUCK + 1];
    __shared__ int gbase[NBUCK];
    __shared__ unsigned char bkof[CHUNK];         // 8 KiB
    const int tid = threadIdx.x;
    const int base = blockIdx.x * CHUNK;
    const int n = min(CHUNK, NE - base);
    for (int i = tid; i < NBUCK; i += PTH) hist[i] = 0;
    __syncthreads();
    for (int i = tid; i < n; i += PTH) atomicAdd(&hist[dst[base + i] >> BSH], 1);
    __syncthreads();
    if (tid < 64) {                                // exclusive scan of hist
        int carry = 0;
        #pragma unroll
        for (int g = 0; g < 4; ++g) {
            int b = g * 64 + tid;
            int v = (b < NBUCK) ? hist[b] : 0;
            int s = v;
            #pragma unroll
            for (int o = 1; o < 64; o <<= 1) { int t = __shfl_up(s, o, 64); if (tid >= o) s += t; }
            if (b < NBUCK) lstart[b] = carry + s - v;
            carry += __shfl(s, 63, 64);
        }
        if (tid == 0) lstart[NBUCK] = n;
    }
    __syncthreads();
    for (int b = tid; b < NBUCK; b += PTH) {
        int cnt = lstart[b + 1] - lstart[b];
        gbase[b] = atomicAdd(&gcur[b], cnt);
        hist[b] = lstart[b];
    }
    __syncthreads();
    for (int i = tid; i < n; i += PTH) {
        int e = base + i;
        int s = src[e], d = dst[e];
        int bk = d >> BSH;
        int p = atomicAdd(&hist[bk], 1);
        stage[p] = ((unsigned long long)__float_as_uint(attr[e]) << 32)
                 | (unsigned)(s | ((d & (BNODES - 1)) << 17));
        bkof[p] = (unsigned char)bk;
    }
    __syncthreads();
    for (int i = tid; i < n; i += PTH) {
        int bk = bkof[i];
        part[(size_t)gbase[bk] + (i - lstart[bk])] = stage[i];
    }
}

// per-bucket degree histogram + PADDED (mult-8) local scan.
// rowptr[node] <- local padded offset; dinvf <- rsqrt(deg); pbsum[b] <- padded total
__global__ void __launch_bounds__(512) k_ndeg(const int* __restrict__ gcur,
        const unsigned long long* __restrict__ part,
        int* __restrict__ rowptr, float* __restrict__ dinvf, int* __restrict__ pbsum) {
    __shared__ int h[BNODES];
    __shared__ int wsum[8];
    const int b = blockIdx.x, tid = threadIdx.x;
    const int lane = tid & 63, wv = tid >> 6;
    h[tid] = 0;
    __syncthreads();
    const int rs = b * CAP, re = gcur[b];
    for (int j = rs + tid; j < re; j += 512) {
        unsigned lo = (unsigned)part[j];
        atomicAdd(&h[(lo >> 17) & (BNODES - 1)], 1);
    }
    __syncthreads();
    int deg = h[tid];
    int pd = (deg + 7) & ~7;
    int x = pd;
    #pragma unroll
    for (int o = 1; o < 64; o <<= 1) { int t = __shfl_up(x, o, 64); if (lane >= o) x += t; }
    if (lane == 63) wsum[wv] = x;
    __syncthreads();
    if (tid < 8) {
        int orig = wsum[tid]; int t = orig;
        #pragma unroll
        for (int o = 1; o < 8; o <<= 1) { int u = __shfl_up(t, o, 64); if (tid >= o) t += u; }
        wsum[tid] = t - orig;
    }
    __syncthreads();
    int node = b * BNODES + tid;
    int lofs = wsum[wv] + (x - pd);              // exclusive padded offset in bucket
    if (node < NN) {
        rowptr[node] = lofs;
        dinvf[node] = (deg > 0) ? rsqrtf((float)deg) : 0.0f;
    }
    if (tid == 511) pbsum[b] = wsum[7] + x;      // bucket padded total
}

// scan pbsum -> pbase[NBUCK+1]; rowptr[NN] = grand padded total
__global__ void k_pbscan(const int* __restrict__ pbsum, int* __restrict__ pbase,
                         int* __restrict__ rowptr) {
    int tid = threadIdx.x;  // 64
    int carry = 0;
    #pragma unroll
    for (int g = 0; g < 4; ++g) {
        int b = g * 64 + tid;
        int v = (b < NBUCK) ? pbsum[b] : 0;
        int s = v;
        #pragma unroll
        for (int o = 1; o < 64; o <<= 1) { int t = __shfl_up(s, o, 64); if (tid >= o) s += t; }
        if (b < NBUCK) pbase[b] = carry + s - v;
        carry += __shfl(s, 63, 64);
    }
    if (tid == 0) { pbase[NBUCK] = carry; rowptr[NN] = carry; }
}

// pass 2: coef + exact placement into padded slots; zero the pad; finalize rowptr
__global__ void __launch_bounds__(512) k_place(const int* __restrict__ gcur,
        const int* __restrict__ pbase, const int* __restrict__ pbsum,
        const unsigned long long* __restrict__ part,
        const float* __restrict__ dinvf, const float* __restrict__ scale,
        int* __restrict__ rowptr, int* __restrict__ es, __half* __restrict__ ew) {
    __shared__ int cur[BNODES];
    __shared__ int lofs_s[BNODES];
    __shared__ float dli[BNODES];
    const int b = blockIdx.x, tid = threadIdx.x;
    const int node = b * BNODES + tid;
    const int base = pbase[b];
    const int ltot = pbsum[b];
    int lofs = (node < NN) ? rowptr[node] : ltot;
    lofs_s[tid] = lofs;
    cur[tid] = base + lofs;
    dli[tid] = (node < NN) ? dinvf[node] : 0.0f;
    __syncthreads();
    const int rs = b * CAP, re = gcur[b];
    const float sc = scale[0];
    for (int j = rs + tid; j < re; j += 512) {
        unsigned long long v = part[j];
        unsigned lo = (unsigned)v;
        int s  = lo & 0x1FFFF;
        int dl = (lo >> 17) & (BNODES - 1);
        float at = __uint_as_float((unsigned)(v >> 32));
        float c = dinvf[s] * dli[dl] * expf(sc * at);
        int p = atomicAdd(&cur[dl], 1);
        es[p] = s;
        ew[p] = __float2half(c);
    }
    __syncthreads();
    int rowend = base + ((tid == 511) ? ltot : lofs_s[tid + 1]);
    for (int p = cur[tid]; p < rowend; ++p) { es[p] = 0; ew[p] = __float2half(0.0f); }
    if (node < NN) rowptr[node] = base + lofs;   // final padded row start
}

// x0 = fp16(emb). grid = NN*ED/4/256 = 6250 exact
__global__ void k_prep(const float* __restrict__ emb, unsigned short* __restrict__ x0) {
    int i = blockIdx.x * 256 + threadIdx.x;
    float4 e = reinterpret_cast<const float4*>(emb)[i];
    ushort4 u;
    u.x = __half_as_ushort(__float2half(e.x));
    u.y = __half_as_ushort(__float2half(e.y));
    u.z = __half_as_ushort(__float2half(e.z));
    u.w = __half_as_ushort(__float2half(e.w));
    reinterpret_cast<ushort4*>(x0)[i] = u;
}

// gather: one wave per node; 4 lane-groups of 16 handle 4 edges (a quad);
// each lane loads uint2 = 4 fp16 dims; packed v_pk_fma_f16 accumulation;
// 16-edge main loop (4 x-loads in flight per lane) + 8-edge tail.
// FINAL: fused epilogue writes out0 = emb and acc = w0*emb+w1*y1+w2*y2+w3*P(y2).
template <bool FINAL>
__global__ void __launch_bounds__(256) k_gather(const int* __restrict__ rowptr,
        const int* __restrict__ es, const __half* __restrict__ ew,
        const unsigned short* __restrict__ x, unsigned short* __restrict__ y,
        const unsigned short* __restrict__ y1, const float* __restrict__ emb,
        const float* __restrict__ attnp, float* __restrict__ out0,
        float* __restrict__ acc) {
    int gt = blockIdx.x * 256 + threadIdx.x;   // grid = NN*64/256 = 25000 exact
    int nid = gt >> 6;                         // wave-uniform
    int lane = gt & 63;
    int g = lane >> 4;                         // edge slot 0..3 within quad
    int gi = lane & 15;                        // 4-dim chunk index
    int beg = __builtin_amdgcn_readfirstlane(rowptr[nid]);
    int end = __builtin_amdgcn_readfirstlane(rowptr[nid + 1]);
    // byte-perm selector: duplicate lo half (g even) or hi half (g odd) of wp
    const unsigned wsel = (g & 1) ? 0x03020302u : 0x01000100u;
    const unsigned* ewu = reinterpret_cast<const unsigned*>(ew);
    const uint2* xv = reinterpret_cast<const uint2*>(x);
    __half2 pa0 = __float2half2_rn(0.0f), pa1 = pa0, pb0 = pa0, pb1 = pa0;

#define QUAD(JJ, A0, A1) { \
    int s0 = es[JJ], s1 = es[(JJ) + 1], s2 = es[(JJ) + 2], s3 = es[(JJ) + 3]; \
    unsigned w01 = ewu[(JJ) >> 1], w23 = ewu[((JJ) >> 1) + 1]; \
    int sA = (g & 1) ? s1 : s0; \
    int sB = (g & 1) ? s3 : s2; \
    int s = (g & 2) ? sB : sA; \
    unsigned wp = (g & 2) ? w23 : w01; \
    U32H2 wd; wd.u = __builtin_amdgcn_perm(wp, wp, wsel); \
    uint2 u = xv[(size_t)s * 16 + gi]; \
    U32H2 ux, uy; ux.u = u.x; uy.u = u.y; \
    A0 = __hfma2(wd.h, ux.h, A0); \
    A1 = __hfma2(wd.h, uy.h, A1); }

    int j = beg;
    int n16 = beg + ((end - beg) & ~15);
    for (; j < n16; j += 16) {
        QUAD(j,      pa0, pa1);
        QUAD(j + 4,  pb0, pb1);
        QUAD(j + 8,  pa0, pa1);
        QUAD(j + 12, pb0, pb1);
    }
    if (j < end) {                             // 8-edge tail (wave-uniform branch)
        QUAD(j,     pa0, pa1);
        QUAD(j + 4, pb0, pb1);
    }
#undef QUAD

    float2 fa0 = __half22float2(pa0), fb0 = __half22float2(pb0);
    float2 fa1 = __half22float2(pa1), fb1 = __half22float2(pb1);
    float a0 = fa0.x + fb0.x;                  // dim 4gi+0
    float a1 = fa0.y + fb0.y;                  // dim 4gi+1
    float a2 = fa1.x + fb1.x;                  // dim 4gi+2
    float a3 = fa1.y + fb1.y;                  // dim 4gi+3
    a0 += __shfl_xor(a0, 16, 64); a0 += __shfl_xor(a0, 32, 64);
    a1 += __shfl_xor(a1, 16, 64); a1 += __shfl_xor(a1, 32, 64);
    a2 += __shfl_xor(a2, 16, 64); a2 += __shfl_xor(a2, 32, 64);
    a3 += __shfl_xor(a3, 16, 64); a3 += __shfl_xor(a3, 32, 64);
    if (lane < 16) {
        size_t ri = (size_t)nid * 16 + gi;     // uint2-granular row slot
        if (!FINAL) {
            U32H2 o01, o23;
            o01.h = __floats2half2_rn(a0, a1);
            o23.h = __floats2half2_rn(a2, a3);
            uint2 o; o.x = o01.u; o.y = o23.u;
            reinterpret_cast<uint2*>(y)[ri] = o;
        } else {
            float w0 = attnp[0], w1 = attnp[1], w2 = attnp[2], w3 = attnp[3];
            float4 e = reinterpret_cast<const float4*>(emb)[ri];
            uint2 v1 = reinterpret_cast<const uint2*>(y1)[ri];
            uint2 v2 = xv[ri];                 // y2 row of this node
            float4 r;
            r.x = w0 * e.x + w1 * h2lo(v1.x) + w2 * h2lo(v2.x) + w3 * a0;
            r.y = w0 * e.y + w1 * h2hi(v1.x) + w2 * h2hi(v2.x) + w3 * a1;
            r.z = w0 * e.z + w1 * h2lo(v1.y) + w2 * h2lo(v2.y) + w3 * a2;
            r.w = w0 * e.w + w1 * h2hi(v1.y) + w2 * h2hi(v2.y) + w3 * a3;
            reinterpret_cast<float4*>(out0)[ri] = e;
            reinterpret_cast<float4*>(acc)[ri] = r;
        }
    }
}

extern "C" void kernel_launch(void* const* d_in, const int* in_sizes, int n_in,
                              void* d_out, int out_size, void* d_ws, size_t ws_size,
                              hipStream_t stream) {
    const float* emb   = (const float*)d_in[0];
    const float* attw  = (const float*)d_in[1];
    const float* scale = (const float*)d_in[2];
    const float* attr  = (const float*)d_in[3];
    const int*   ei    = (const int*)d_in[4];
    const int* src = ei;
    const int* dst = ei + NE;

    float* out0 = (float*)d_out;
    float* acc  = out0 + (size_t)NN * ED;

    // workspace (~65 MB). part (27.3MB) dead after k_place -> aliased by x0,y1.
    const size_t SLOTS = (size_t)NBUCK * CAP;   // 3,411,968
    char* ws = (char*)d_ws;
    size_t off = 0;
    float*  attn  = (float*)(ws + off); off += 256;
    int*    gcur  = (int*)(ws + off);   off += 1024;
    int*    pbsum = (int*)(ws + off);   off += 1024;
    int*    pbase = (int*)(ws + off);   off += 1024;
    float*  dinvf = (float*)(ws + off); off += ((size_t)NN * 4 + 255) & ~(size_t)255;
    int*    rowptr= (int*)(ws + off);   off += ((size_t)(NN + 1) * 4 + 255) & ~(size_t)255;
    unsigned long long* part = (unsigned long long*)(ws + off); off += SLOTS * 8;
    int*    es    = (int*)(ws + off);   off += (size_t)NEP * 4;
    __half* ew    = (__half*)(ws + off);off += (size_t)NEP * 2;
    unsigned short* y2 = (unsigned short*)(ws + off); off += (size_t)NN * ED * 2;
    unsigned short* x0 = (unsigned short*)part;                     // alias
    unsigned short* y1 = (unsigned short*)part + (size_t)NN * ED;   // alias

    const int VB = (NN * ED / 4) / 256;        // 6250 exact
    const int GB = (NN * ED) / 256;            // 25000 exact
    const int PB = (NE + CHUNK - 1) / CHUNK;   // 391

    k_init<<<1, 256, 0, stream>>>(attw, attn, gcur);
    k_part<<<PB, PTH, 0, stream>>>(src, dst, attr, gcur, part);
    k_ndeg<<<NBUCK, 512, 0, stream>>>(gcur, part, rowptr, dinvf, pbsum);
    k_pbscan<<<1, 64, 0, stream>>>(pbsum, pbase, rowptr);
    k_place<<<NBUCK, 512, 0, stream>>>(gcur, pbase, pbsum, part, dinvf,
                                       scale, rowptr, es, ew);

    k_prep<<<VB, 256, 0, stream>>>(emb, x0);   // part dead; x0/y1 alias it

    k_gather<false><<<GB, 256, 0, stream>>>(rowptr, es, ew, x0, y1, nullptr, nullptr, nullptr, nullptr, nullptr);
    k_gather<false><<<GB, 256, 0, stream>>>(rowptr, es, ew, y1, y2, nullptr, nullptr, nullptr, nullptr, nullptr);
    k_gather<true><<<GB, 256, 0, stream>>>(rowptr, es, ew, y2, nullptr, y1, emb, attn, out0, acc);
}